// Round 6
// baseline (3223.860 us; speedup 1.0000x reference)
//
#include <hip/hip_runtime.h>
#include <math.h>

typedef _Float16 half_t;
typedef _Float16 half8 __attribute__((ext_vector_type(8)));
typedef float floatx16 __attribute__((ext_vector_type(16)));
typedef unsigned int uint;

#define HD 512
#define BB 512
#define TT 336
#define HOR 48
#define NBLOCK 256
#define NTHREAD 512
#define GBLK 32   // blocks per XCD group (capacity-forced: 128KB LDS -> 1 block/CU)
#define MFMA16(a,b,c) __builtin_amdgcn_mfma_f32_32x32x16_f16(a, b, c, 0, 0, 0)

__device__ __forceinline__ float sig_(float x) { return 1.0f / (1.0f + __expf(-x)); }

// ---------------------------------------------------------------------------
// Weight prep: fp32 [rows][512] -> fp16 frag-linear for mfma_f32_32x32x16_f16.
// Entry t = ((jt*NG + g)*NKC + kc)*64 + lane holds 8 halves:
//   W[g*512 + jt*32 + (lane&31)][kc*16 + (lane>>5)*8 + i]
// ---------------------------------------------------------------------------
__global__ __launch_bounds__(256)
void prep_w2(const float* __restrict__ W1, const float* __restrict__ W2,
             half_t* __restrict__ D, int NKC, int NG)
{
    const int t = blockIdx.x * 256 + threadIdx.x;
    if (t >= 16 * NG * NKC * 64) return;
    const int lane = t & 63;
    const int kc = (t >> 6) % NKC;
    const int jtg = (t >> 6) / NKC;
    const int g = jtg % NG, jt = jtg / NG;
    const int row = g * 512 + jt * 32 + (lane & 31);
    const int k = kc * 16 + (lane >> 5) * 8;
    const float* Wp = (k < 512) ? W1 : W2;
    const int kk = (k < 512) ? k : (k - 512);
    const float4 lo = *(const float4*)(Wp + (size_t)row * 512 + kk);
    const float4 hi = *(const float4*)(Wp + (size_t)row * 512 + kk + 4);
    half8 h;
    h[0] = (half_t)lo.x; h[1] = (half_t)lo.y; h[2] = (half_t)lo.z; h[3] = (half_t)lo.w;
    h[4] = (half_t)hi.x; h[5] = (half_t)hi.y; h[6] = (half_t)hi.z; h[7] = (half_t)hi.w;
    *(half8*)(D + (size_t)t * 8) = h;
}

// lv partial slot init: pred(s=0) partial for role 0 = last src value - fcb.
__global__ void lv_init_kernel(const float* __restrict__ src,
                               const float* __restrict__ fcb,
                               float* __restrict__ lvpart)
{
    const int b = threadIdx.x + blockIdx.x * blockDim.x;
    if (b < BB) {
        const int g = b >> 6, row = b & 63;
        lvpart[((size_t)(g * 2 + 0) * 16 + 0) * 64 + row] =
            src[((size_t)b * TT + (TT - 1)) * 8] - fcb[0];
    }
}

// ---------------------------------------------------------------------------
struct PP {
    const half_t *BL0, *BWih1, *BWhh1, *Bcwhh, *Blin;
    half_t *h0f[2], *h1f[2], *hdf[2];
    float *hd32row;
    const float *src, *tff, *Wih0;
    const float *bih0, *bhh0, *bih1, *bhh1, *dec0b, *cWih, *cbih, *cbhh, *fcW, *fcb;
    float *lvpart, *out;
    uint *bars;
    int *tickets;
};

// Distributed-slot XCD barrier: no RMW contention. Each block STORES its local
// step count to its own 64B slot; 32 lanes poll all slots in parallel (one
// vector load per round). Data coherence: producer stores drained to XCD-L2 by
// syncthreads' vmcnt(0) before arrival store; readers invalidate L1 only.
__device__ __forceinline__ void xcd_barrier(uint* slots, int role, uint target)
{
    __syncthreads();
    if (threadIdx.x == 0)
        __hip_atomic_store(slots + role * 16, target, __ATOMIC_RELAXED, __HIP_MEMORY_SCOPE_AGENT);
    if (threadIdx.x < GBLK) {
        while (__hip_atomic_load(slots + threadIdx.x * 16, __ATOMIC_RELAXED,
                                 __HIP_MEMORY_SCOPE_AGENT) < target)
            __builtin_amdgcn_s_sleep(1);
    }
    asm volatile("buffer_inv sc0" ::: "memory");   // L1-only invalidate
    __syncthreads();
}

__device__ __forceinline__ void dump_acc(float* red, int wv, int jl, int hi, const floatx16& a)
{
    #pragma unroll
    for (int rg = 0; rg < 16; ++rg)
        red[wv * 1024 + ((rg & 3) + 8 * (rg >> 2) + 4 * hi) * 32 + jl] = a[rg];
}
__device__ __forceinline__ void sum4(const float* red, int q, int jc, float* o)
{
    #pragma unroll
    for (int c = 0; c < 4; ++c) {
        const int ra = q * 4 + c, mi = ra >> 5, base = (ra & 31) * 32 + jc;
        o[c] = red[(0 + mi) * 1024 + base] + red[(2 + mi) * 1024 + base]
             + red[(4 + mi) * 1024 + base] + red[(6 + mi) * 1024 + base];
    }
}
__device__ __forceinline__ void sum22(const float* red, int q, int jc, float* lo, float* ho)
{
    #pragma unroll
    for (int c = 0; c < 4; ++c) {
        const int ra = q * 4 + c, mi = ra >> 5, base = (ra & 31) * 32 + jc;
        lo[c] = red[(0 + mi) * 1024 + base] + red[(2 + mi) * 1024 + base];
        ho[c] = red[(4 + mi) * 1024 + base] + red[(6 + mi) * 1024 + base];
    }
}

// Load a 3*32*512-half weight slice into LDS, 16-slot XOR swizzle.
__device__ __forceinline__ void load_wlds(half_t* wlds, const half_t* Bsrc, int tid)
{
    #pragma unroll
    for (int it = 0; it < 12; ++it) {
        const int e = it * 512 + tid;
        const int gg = e >> 11, kc = (e >> 6) & 31, ln = e & 63;
        const int jj = ln & 31, h2 = ln >> 5;
        const half8 v = *(const half8*)(Bsrc + (size_t)e * 8);
        *(half8*)&wlds[(size_t)(gg * 32 + jj) * 512 + ((kc * 16 + h2 * 8) ^ ((jj & 15) << 3))] = v;
    }
}

// ---------------------------------------------------------------------------
__global__ __launch_bounds__(NTHREAD, 2)
void rnn_persist(PP p)
{
    __shared__ half_t wlds[3 * 32 * 512];   // 96 KB resident weight slice
    __shared__ float  red[8 * 1024];        // 32 KB K-split reduce buffer
    __shared__ int    meta[2];
    __shared__ float  lvsh[64];

    const int tid = threadIdx.x;
    if (tid == 0) {
        int xcc;
        asm volatile("s_getreg_b32 %0, hwreg(HW_REG_XCC_ID)" : "=s"(xcc));
        xcc &= 7;
        meta[0] = xcc;
        meta[1] = atomicAdd(p.tickets + xcc, 1);
    }
    __syncthreads();
    const int g = meta[0];
    const int role = meta[1] & 31;
    const int L = role >> 4, jt = role & 15;   // L=0: layer0/dec-cell; L=1: layer1/lin

    const int wv = tid >> 6, lane = tid & 63;
    const int jl = lane & 31, hi = lane >> 5;
    const int mi = wv & 1, kh = wv >> 1;       // wave = K-split (kh) x M-tile (mi)
    const int q = tid >> 5, jcell = tid & 31;
    const int row0g = g * 64;
    const int j = jt * 32 + jcell;
    const int swz16 = (jl & 15) << 3;
    const int gbase = g * 32768;
    const int joff = (j >> 4) * 512 + ((j >> 3) & 1) * 256 + (j & 7);

    uint* slots = p.bars + (size_t)g * GBLK * 16;
    uint bcnt = 0;

    load_wlds(wlds, (L ? p.BWhh1 : p.BL0) + (size_t)jt * 6144 * 8, tid);

    // hoisted per-thread constants
    const float* bi = L ? p.bih1 : p.bih0;
    const float* bh = L ? p.bhh1 : p.bhh0;
    const float bir = bi[j] + bh[j];
    const float biz = bi[512 + j] + bh[512 + j];
    const float bin = bi[1024 + j];
    const float bhn = bh[1024 + j];
    float w0r[8], w0z[8], w0n[8];
    if (!L) {
        #pragma unroll
        for (int i = 0; i < 8; ++i) {
            w0r[i] = p.Wih0[(size_t)j * 8 + i];
            w0z[i] = p.Wih0[(size_t)(512 + j) * 8 + i];
            w0n[i] = p.Wih0[(size_t)(1024 + j) * 8 + i];
        }
    }
    float hp[4] = {0.f, 0.f, 0.f, 0.f};   // register-resident previous h

    // ===================== encoder supersteps =====================
    for (int s = 0; s <= TT; ++s) {
        if (!L && s < TT) {
            floatx16 ar = {}, az = {}, an = {};
            const half_t* A = p.h0f[s & 1] + (size_t)(((g * 2 + mi) * 32 + kh * 8) * 64 + lane) * 8;
            #pragma unroll
            for (int kc = 0; kc < 8; ++kc) {
                const half8 a = *(const half8*)(A + kc * 512);
                const int ko = (kh * 128 + kc * 16 + hi * 8) ^ swz16;
                ar = MFMA16(a, *(const half8*)&wlds[(size_t)(0 * 32 + jl) * 512 + ko], ar);
                az = MFMA16(a, *(const half8*)&wlds[(size_t)(1 * 32 + jl) * 512 + ko], az);
                an = MFMA16(a, *(const half8*)&wlds[(size_t)(2 * 32 + jl) * 512 + ko], an);
            }
            float gr[4], gz[4], gn[4];
            dump_acc(red, wv, jl, hi, ar); __syncthreads(); sum4(red, q, jcell, gr); __syncthreads();
            dump_acc(red, wv, jl, hi, az); __syncthreads(); sum4(red, q, jcell, gz); __syncthreads();
            dump_acc(red, wv, jl, hi, an); __syncthreads(); sum4(red, q, jcell, gn);

            half_t* hofr = p.h0f[(s + 1) & 1];
            #pragma unroll
            for (int c = 0; c < 4; ++c) {
                const int r = q * 4 + c;
                const int br = row0g + r;
                const float* sp = p.src + ((size_t)br * TT + s) * 8;
                float xr = gr[c] + bir, xz = gz[c] + biz, xn = bin;
                #pragma unroll
                for (int i = 0; i < 8; ++i) {
                    const float xi = sp[i];
                    xr = fmaf(xi, w0r[i], xr);
                    xz = fmaf(xi, w0z[i], xz);
                    xn = fmaf(xi, w0n[i], xn);
                }
                const float rr = sig_(xr), zz = sig_(xz);
                const float nn = tanhf(xn + rr * (gn[c] + bhn));
                const float h = (1.f - zz) * nn + zz * hp[c];
                hp[c] = h;
                hofr[gbase + (r >> 5) * 16384 + (r & 31) * 8 + joff] = (half_t)h;
            }
        } else if (L && s >= 1) {
            floatx16 ar = {}, az = {}, an = {};
            if (kh < 2) {   // K in [kh*256,+256): A=h0 frag, B=Wih1 streamed (L2-hot)
                const half_t* A = p.h0f[s & 1] + (size_t)(((g * 2 + mi) * 32 + kh * 16) * 64 + lane) * 8;
                const half_t* Bb = p.BWih1 + ((size_t)jt * 6144 + kh * 1024 + lane) * 8;
                #pragma unroll 8
                for (int kc = 0; kc < 16; ++kc) {
                    const half8 a  = *(const half8*)(A + kc * 512);
                    const half8 u0 = *(const half8*)(Bb + (size_t)kc * 512);
                    const half8 u1 = *(const half8*)(Bb + (size_t)kc * 512 + 16384);
                    const half8 u2 = *(const half8*)(Bb + (size_t)kc * 512 + 32768);
                    ar = MFMA16(a, u0, ar);
                    az = MFMA16(a, u1, az);
                    an = MFMA16(a, u2, an);   // i_n partial
                }
            } else {        // K in [512+(kh-2)*256,+256): A=h1 frag, B=Whh1 (LDS)
                const half_t* A = p.h1f[s & 1] + (size_t)(((g * 2 + mi) * 32 + (kh - 2) * 16) * 64 + lane) * 8;
                #pragma unroll
                for (int kc = 0; kc < 16; ++kc) {
                    const half8 a = *(const half8*)(A + kc * 512);
                    const int ko = ((kh - 2) * 256 + kc * 16 + hi * 8) ^ swz16;
                    ar = MFMA16(a, *(const half8*)&wlds[(size_t)(0 * 32 + jl) * 512 + ko], ar);
                    az = MFMA16(a, *(const half8*)&wlds[(size_t)(1 * 32 + jl) * 512 + ko], az);
                    an = MFMA16(a, *(const half8*)&wlds[(size_t)(2 * 32 + jl) * 512 + ko], an);  // h_n partial
                }
            }
            float gr[4], gz[4], gnl[4], gnh[4];
            dump_acc(red, wv, jl, hi, ar); __syncthreads(); sum4(red, q, jcell, gr); __syncthreads();
            dump_acc(red, wv, jl, hi, az); __syncthreads(); sum4(red, q, jcell, gz); __syncthreads();
            dump_acc(red, wv, jl, hi, an); __syncthreads(); sum22(red, q, jcell, gnl, gnh);

            half_t* hofr = p.h1f[(s + 1) & 1];
            #pragma unroll
            for (int c = 0; c < 4; ++c) {
                const int r = q * 4 + c;
                const float rr = sig_(gr[c] + bir), zz = sig_(gz[c] + biz);
                const float nn = tanhf(gnl[c] + bin + rr * (gnh[c] + bhn));
                const float h = (1.f - zz) * nn + zz * hp[c];
                hp[c] = h;
                hofr[gbase + (r >> 5) * 16384 + (r & 31) * 8 + joff] = (half_t)h;
            }
        }
        xcd_barrier(slots, role, ++bcnt);
    }

    // ============ transition: L0 reload dec weights; L1 does linear ============
    if (!L) {
        load_wlds(wlds, p.Bcwhh + (size_t)jt * 6144 * 8, tid);
    } else {
        floatx16 a0 = {};
        const half_t* A = p.h1f[1] + (size_t)(((g * 2 + mi) * 32 + kh * 8) * 64 + lane) * 8;
        const half_t* Bb = p.Blin + ((size_t)jt * 2048 + kh * 512 + lane) * 8;
        #pragma unroll
        for (int kc = 0; kc < 8; ++kc) {
            const half8 a = *(const half8*)(A + kc * 512);
            const half8 w = *(const half8*)(Bb + (size_t)kc * 512);
            a0 = MFMA16(a, w, a0);
        }
        float hv[4];
        dump_acc(red, wv, jl, hi, a0); __syncthreads(); sum4(red, q, jcell, hv);
        const float bj = p.dec0b[j];
        #pragma unroll
        for (int c = 0; c < 4; ++c) {
            const int r = q * 4 + c;
            const float h = hv[c] + bj;
            p.hd32row[(size_t)(row0g + r) * 512 + j] = h;
            p.hdf[0][gbase + (r >> 5) * 16384 + (r & 31) * 8 + joff] = (half_t)h;
        }
    }
    xcd_barrier(slots, role, ++bcnt);

    // ===================== decoder =====================
    float wR[9], wZ[9], wN[9];
    float dbr = 0.f, dbz = 0.f, dbn = 0.f, dbhn = 0.f, fw = 0.f, f0 = 0.f;
    if (!L) {
        #pragma unroll
        for (int i = 0; i < 9; ++i) {
            wR[i] = p.cWih[(size_t)j * 9 + i];
            wZ[i] = p.cWih[(size_t)(512 + j) * 9 + i];
            wN[i] = p.cWih[(size_t)(1024 + j) * 9 + i];
        }
        dbr = p.cbih[j] + p.cbhh[j];
        dbz = p.cbih[512 + j] + p.cbhh[512 + j];
        dbn = p.cbih[1024 + j];
        dbhn = p.cbhh[1024 + j];
        fw = p.fcW[j];
        f0 = p.fcb[0];
    }
    for (int s = 0; s < HOR; ++s) {
        // gather lv: sum the 16 per-role partials written last step (L2-local)
        if (!L && tid < 64) {
            const float* lp = p.lvpart + ((size_t)(g * 2 + (s & 1)) * 16) * 64 + tid;
            float acc = 0.f;
            #pragma unroll
            for (int rr = 0; rr < 16; ++rr) acc += lp[rr * 64];
            lvsh[tid] = acc;
        }
        __syncthreads();
        if (!L) {
            floatx16 ar = {}, az = {}, an = {};
            const half_t* A = p.hdf[s & 1] + (size_t)(((g * 2 + mi) * 32 + kh * 8) * 64 + lane) * 8;
            #pragma unroll
            for (int kc = 0; kc < 8; ++kc) {
                const half8 a = *(const half8*)(A + kc * 512);
                const int ko = (kh * 128 + kc * 16 + hi * 8) ^ swz16;
                ar = MFMA16(a, *(const half8*)&wlds[(size_t)(0 * 32 + jl) * 512 + ko], ar);
                az = MFMA16(a, *(const half8*)&wlds[(size_t)(1 * 32 + jl) * 512 + ko], az);
                an = MFMA16(a, *(const half8*)&wlds[(size_t)(2 * 32 + jl) * 512 + ko], an);
            }
            float gr[4], gz[4], gn[4];
            dump_acc(red, wv, jl, hi, ar); __syncthreads(); sum4(red, q, jcell, gr); __syncthreads();
            dump_acc(red, wv, jl, hi, az); __syncthreads(); sum4(red, q, jcell, gz); __syncthreads();
            dump_acc(red, wv, jl, hi, an); __syncthreads(); sum4(red, q, jcell, gn);

            half_t* hofr = p.hdf[(s + 1) & 1];
            #pragma unroll
            for (int c = 0; c < 4; ++c) {
                const int r = q * 4 + c;
                const int br = row0g + r;
                if (s == 0) hp[c] = p.hd32row[(size_t)br * 512 + j];
                const float x0 = lvsh[r] + f0;
                const float* sp = p.tff + ((size_t)br * HOR + s) * 8;
                float xr = gr[c] + dbr + x0 * wR[0];
                float xz = gz[c] + dbz + x0 * wZ[0];
                float xn = dbn + x0 * wN[0];
                #pragma unroll
                for (int i = 0; i < 8; ++i) {
                    const float xi = sp[i];
                    xr = fmaf(xi, wR[1 + i], xr);
                    xz = fmaf(xi, wZ[1 + i], xz);
                    xn = fmaf(xi, wN[1 + i], xn);
                }
                const float rr = sig_(xr), zz = sig_(xz);
                const float nn = tanhf(xn + rr * (gn[c] + dbhn));
                const float h = (1.f - zz) * nn + zz * hp[c];
                hp[c] = h;
                hofr[gbase + (r >> 5) * 16384 + (r & 31) * 8 + joff] = (half_t)h;

                float v = h * fw;
                #pragma unroll
                for (int off = 16; off > 0; off >>= 1) v += __shfl_xor(v, off);
                if ((lane & 31) == 0) {
                    // per-role partial slot (plain L2 store; consumer sums after barrier)
                    p.lvpart[((size_t)(g * 2 + ((s + 1) & 1)) * 16 + jt) * 64 + r] = v;
                    atomicAdd(p.out + (size_t)br * HOR + s, v + (role == 0 ? f0 : 0.f));
                }
            }
        }
        xcd_barrier(slots, role, ++bcnt);
    }
}

// ---------------------------------------------------------------------------
extern "C" void kernel_launch(void* const* d_in, const int* in_sizes, int n_in,
                              void* d_out, int out_size, void* d_ws, size_t ws_size,
                              hipStream_t stream)
{
    const float* src   = (const float*)d_in[0];
    const float* tff   = (const float*)d_in[1];
    const float* Wih0  = (const float*)d_in[2];
    const float* Whh0  = (const float*)d_in[3];
    const float* bih0  = (const float*)d_in[4];
    const float* bhh0  = (const float*)d_in[5];
    const float* Wih1  = (const float*)d_in[6];
    const float* Whh1  = (const float*)d_in[7];
    const float* bih1  = (const float*)d_in[8];
    const float* bhh1  = (const float*)d_in[9];
    const float* dec0W = (const float*)d_in[10];
    const float* dec0b = (const float*)d_in[11];
    const float* cWih  = (const float*)d_in[12];
    const float* cWhh  = (const float*)d_in[13];
    const float* cbih  = (const float*)d_in[14];
    const float* cbhh  = (const float*)d_in[15];
    const float* fcW   = (const float*)d_in[16];
    const float* fcb   = (const float*)d_in[17];
    float* out = (float*)d_out;
    float* ws  = (float*)d_ws;

    constexpr size_t NFRAG = 131072;   // one frag h-buffer, in float units

    PP pp;
    size_t off = 0;
    // ---- zero region (single memset) ----
    pp.h0f[0] = (half_t*)(ws + off); off += NFRAG;
    pp.h1f[1] = (half_t*)(ws + off); off += NFRAG;
    pp.lvpart = ws + off; off += 8 * 2 * 16 * 64;          // [g][par][role][row]
    pp.bars   = (uint*)(ws + off); off += 8 * GBLK * 16;   // 64B-padded slots
    pp.tickets = (int*)(ws + off); off += 64;
    const size_t zero_floats = off;
    // ---- rest ----
    pp.h0f[1] = (half_t*)(ws + off); off += NFRAG;
    pp.h1f[0] = (half_t*)(ws + off); off += NFRAG;
    pp.hdf[0] = (half_t*)(ws + off); off += NFRAG;
    pp.hdf[1] = (half_t*)(ws + off); off += NFRAG;
    pp.hd32row = ws + off; off += (size_t)BB * HD;
    half_t* BL0   = (half_t*)(ws + off); off += 393216;
    half_t* BWih1 = (half_t*)(ws + off); off += 393216;
    half_t* BWhh1 = (half_t*)(ws + off); off += 393216;
    half_t* Bcwhh = (half_t*)(ws + off); off += 393216;
    half_t* Blin  = (half_t*)(ws + off); off += 131072;

    pp.BL0 = BL0; pp.BWih1 = BWih1; pp.BWhh1 = BWhh1; pp.Bcwhh = Bcwhh; pp.Blin = Blin;
    pp.src = src; pp.tff = tff; pp.Wih0 = Wih0;
    pp.bih0 = bih0; pp.bhh0 = bhh0; pp.bih1 = bih1; pp.bhh1 = bhh1;
    pp.dec0b = dec0b; pp.cWih = cWih; pp.cbih = cbih; pp.cbhh = cbhh;
    pp.fcW = fcW; pp.fcb = fcb; pp.out = out;

    // ---- prep ----
    hipMemsetAsync(ws, 0, zero_floats * sizeof(float), stream);
    hipMemsetAsync(out, 0, (size_t)BB * HOR * sizeof(float), stream);
    prep_w2<<<384, 256, 0, stream>>>(Whh0, Whh0, BL0, 32, 3);
    prep_w2<<<384, 256, 0, stream>>>(Wih1, Wih1, BWih1, 32, 3);
    prep_w2<<<384, 256, 0, stream>>>(Whh1, Whh1, BWhh1, 32, 3);
    prep_w2<<<384, 256, 0, stream>>>(cWhh, cWhh, Bcwhh, 32, 3);
    prep_w2<<<128, 256, 0, stream>>>(dec0W, dec0W, Blin, 32, 1);
    lv_init_kernel<<<1, 512, 0, stream>>>(src, fcb, pp.lvpart);

    // ---- persistent cooperative kernel ----
    void* kargs[] = { (void*)&pp };
    hipLaunchCooperativeKernel((const void*)rnn_persist, dim3(NBLOCK), dim3(NTHREAD),
                               kargs, 0, stream);
}

// Round 7
// 2360.874 us; speedup vs baseline: 1.3655x; 1.3655x over previous
//
#include <hip/hip_runtime.h>
#include <math.h>

typedef _Float16 half_t;
typedef _Float16 half8 __attribute__((ext_vector_type(8)));
typedef float floatx4 __attribute__((ext_vector_type(4)));
typedef unsigned int uint;

#define HD 512
#define BB 512
#define TT 336
#define HOR 48
#define NBLOCK 256
#define NTHREAD 256
#define GBLK 32
#define MFMA(a,b,c) __builtin_amdgcn_mfma_f32_16x16x32_f16(a, b, c, 0, 0, 0)

__device__ __forceinline__ float sig_(float x) { return 1.0f / (1.0f + __expf(-x)); }

// ---------------------------------------------------------------------------
// Weight prep: fp32 [ngate*512 rows][512] -> fp16 B-frag linear for
// mfma_f32_16x16x32_f16.  Entry t = ((jt*ngate + g)*16 + ks)*64 + l holds
// 8 halves: W[g*512 + jt*16 + (l&15)][ks*32 + (l>>4)*8 + i]
// ---------------------------------------------------------------------------
__global__ __launch_bounds__(256)
void prep_w3(const float* __restrict__ W, half_t* __restrict__ D, int ngate)
{
    const int t = blockIdx.x * 256 + threadIdx.x;
    if (t >= 32 * ngate * 16 * 64) return;
    const int l = t & 63, ks = (t >> 6) & 15, gj = t >> 10;
    const int g = gj % ngate, jt = gj / ngate;
    const int row = g * 512 + jt * 16 + (l & 15);
    const int k = ks * 32 + (l >> 4) * 8;
    const float4 lo = *(const float4*)(W + (size_t)row * 512 + k);
    const float4 hi = *(const float4*)(W + (size_t)row * 512 + k + 4);
    half8 h;
    h[0] = (half_t)lo.x; h[1] = (half_t)lo.y; h[2] = (half_t)lo.z; h[3] = (half_t)lo.w;
    h[4] = (half_t)hi.x; h[5] = (half_t)hi.y; h[6] = (half_t)hi.z; h[7] = (half_t)hi.w;
    *(half8*)(D + (size_t)t * 8) = h;
}

__global__ void lv_init_kernel(const float* __restrict__ src,
                               const float* __restrict__ fcb,
                               float* __restrict__ lvpart)
{
    const int b = threadIdx.x + blockIdx.x * blockDim.x;
    if (b < BB) {
        const int g = b >> 6, row = b & 63;
        lvpart[((size_t)(g * 2 + 0) * 32 + 0) * 64 + row] =
            src[((size_t)b * TT + (TT - 1)) * 8] - fcb[0];
    }
}

// ---------------------------------------------------------------------------
struct PP {
    const half_t *BL0, *BWih1, *BWhh1, *Bcwhh, *Bdec;
    half_t *h0f[2], *h1f[2], *hdf[2];
    const float *src, *tff, *Wih0;
    const float *bih0, *bhh0, *bih1, *bhh1, *dec0b, *cWih, *cbih, *cbhh, *fcW, *fcb;
    float *lvpart, *out;
    uint *bars;
    int *tickets;
};

// Distributed-slot XCD barrier (round 6; L1-only invalidate, no L2 flush).
__device__ __forceinline__ void xcd_barrier(uint* slots, int role, uint target)
{
    __syncthreads();
    if (threadIdx.x == 0)
        __hip_atomic_store(slots + role * 16, target, __ATOMIC_RELAXED, __HIP_MEMORY_SCOPE_AGENT);
    if (threadIdx.x < GBLK) {
        while (__hip_atomic_load(slots + threadIdx.x * 16, __ATOMIC_RELAXED,
                                 __HIP_MEMORY_SCOPE_AGENT) < target)
            __builtin_amdgcn_s_sleep(1);
    }
    asm volatile("buffer_inv sc0" ::: "memory");
    __syncthreads();
}

// Stage one 48KB weight slice (3 gates x 16 rows x 512 k) into LDS, swizzled.
__device__ __forceinline__ void stage48(half_t* dst, const half_t* src, int tid)
{
    #pragma unroll
    for (int it = 0; it < 12; ++it) {
        const int e = it * 256 + tid;
        const int l = e & 63, ks = (e >> 6) & 15, g = e >> 10;
        const int jl = l & 15;
        const half8 v = *(const half8*)(src + (size_t)e * 8);
        const int d = (g * 16 + jl) * 512 + ((ks * 32 + (l >> 4) * 8) ^ ((jl & 7) << 3));
        *(half8*)(dst + d) = v;
    }
}

// Swizzled B-frag read from a staged LDS slice.
__device__ __forceinline__ half8 bread(const half_t* buf, int g, int ks, int lane)
{
    const int jl = lane & 15;
    const int idx = (g * 16 + jl) * 512 + ((ks * 32 + (lane >> 4) * 8) ^ ((jl & 7) << 3));
    return *(const half8*)(buf + idx);
}

// A-frag base: h frag layout [g][mi(4)][ks(16)][lane(64)][8]
__device__ __forceinline__ const half_t* afrag(const half_t* h, int g, int mi, int lane)
{
    return h + ((size_t)((g * 4 + mi) * 16) * 64 + lane) * 8;
}
// h-store position for C cell (row16, jl) of (g, mi, jt)
__device__ __forceinline__ size_t fragidx(int g, int mi, int jt, int row16, int jl)
{
    const int lanef = row16 + 16 * ((2 * jt + (jl >> 3)) & 3);
    return ((size_t)(((g * 4 + mi) * 16 + (jt >> 1)) * 64) + lanef) * 8 + (jl & 7);
}

// ---------------------------------------------------------------------------
__global__ __launch_bounds__(NTHREAD, 1)
void rnn_persist(PP p)
{
    __shared__ half_t wlds[3 * 24576];   // 144 KB: [Whh0 | Wih1 | Whh1] jt-slices
    __shared__ float  lvsh[64];
    __shared__ int    meta[2];

    const int tid = threadIdx.x;
    if (tid == 0) {
        int xcc;
        asm volatile("s_getreg_b32 %0, hwreg(HW_REG_XCC_ID)" : "=s"(xcc));
        xcc &= 7;
        meta[0] = xcc;
        meta[1] = atomicAdd(p.tickets + xcc, 1);
    }
    __syncthreads();
    const int g = meta[0];
    const int jt = meta[1] & 31;

    const int wv = tid >> 6, lane = tid & 63;
    const int jl = lane & 15, kg = lane >> 4;
    const int j = jt * 16 + jl;
    const int L = wv >> 1, wm = wv & 1;   // L: 0 = layer0 waves, 1 = layer1 waves

    uint* slots = p.bars + (size_t)g * GBLK * 16;
    uint bcnt = 0;

    stage48(wlds,          p.BL0   + (size_t)jt * 24576, tid);
    stage48(wlds + 24576,  p.BWih1 + (size_t)jt * 24576, tid);
    stage48(wlds + 49152,  p.BWhh1 + (size_t)jt * 24576, tid);
    __syncthreads();

    // per-lane constants (one j per lane)
    const float* bi = L ? p.bih1 : p.bih0;
    const float* bh = L ? p.bhh1 : p.bhh0;
    const float bir = bi[j] + bh[j];
    const float biz = bi[512 + j] + bh[512 + j];
    const float bin = bi[1024 + j];
    const float bhn = bh[1024 + j];
    float w0r[8], w0z[8], w0n[8];
    if (!L) {
        #pragma unroll
        for (int i = 0; i < 8; ++i) {
            w0r[i] = p.Wih0[(size_t)j * 8 + i];
            w0z[i] = p.Wih0[(size_t)(512 + j) * 8 + i];
            w0n[i] = p.Wih0[(size_t)(1024 + j) * 8 + i];
        }
    }
    float hp[2][4] = {{0.f,0.f,0.f,0.f},{0.f,0.f,0.f,0.f}};

    // ===================== encoder supersteps =====================
    for (int s = 0; s <= TT; ++s) {
        if (!L && s < TT) {
            // layer 0: h0(s) = GRU0(h0(s-1), x(s)); K=512 from LDS Whh0
            floatx4 aR[2] = {}, aZ[2] = {}, aN[2] = {};
            const half_t* A0 = afrag(p.h0f[s & 1], g, wm * 2, lane);
            #pragma unroll 4
            for (int ks = 0; ks < 16; ++ks) {
                const half8 a0 = *(const half8*)(A0 + ks * 512);
                const half8 a1 = *(const half8*)(A0 + 8192 + ks * 512);
                const half8 br = bread(wlds, 0, ks, lane);
                const half8 bz = bread(wlds, 1, ks, lane);
                const half8 bn = bread(wlds, 2, ks, lane);
                aR[0] = MFMA(a0, br, aR[0]); aR[1] = MFMA(a1, br, aR[1]);
                aZ[0] = MFMA(a0, bz, aZ[0]); aZ[1] = MFMA(a1, bz, aZ[1]);
                aN[0] = MFMA(a0, bn, aN[0]); aN[1] = MFMA(a1, bn, aN[1]);
            }
            half_t* ho = p.h0f[(s + 1) & 1];
            #pragma unroll
            for (int ms = 0; ms < 2; ++ms)
            #pragma unroll
            for (int r = 0; r < 4; ++r) {
                const int row16 = kg * 4 + r;
                const int brw = g * 64 + wm * 32 + ms * 16 + row16;
                const float* sp = p.src + ((size_t)brw * TT + s) * 8;
                float xr = aR[ms][r] + bir, xz = aZ[ms][r] + biz, xn = bin;
                #pragma unroll
                for (int i = 0; i < 8; ++i) {
                    const float xi = sp[i];
                    xr = fmaf(xi, w0r[i], xr);
                    xz = fmaf(xi, w0z[i], xz);
                    xn = fmaf(xi, w0n[i], xn);
                }
                const float rr = sig_(xr), zz = sig_(xz);
                const float nn = tanhf(xn + rr * (aN[ms][r] + bhn));
                const float h = (1.f - zz) * nn + zz * hp[ms][r];
                hp[ms][r] = h;
                ho[fragidx(g, wm * 2 + ms, jt, row16, jl)] = (half_t)h;
            }
        } else if (L && s >= 1) {
            // layer 1: h1(s-1) = GRU1(h1(s-2), h0(s-1)); Wih1+Whh1 from LDS
            floatx4 aR[2] = {}, aZ[2] = {}, aNi[2] = {}, aNh[2] = {};
            const half_t* A0 = afrag(p.h0f[s & 1], g, wm * 2, lane);
            const half_t* A1 = afrag(p.h1f[s & 1], g, wm * 2, lane);
            #pragma unroll 4
            for (int ks = 0; ks < 16; ++ks) {
                const half8 a0 = *(const half8*)(A0 + ks * 512);
                const half8 a1 = *(const half8*)(A0 + 8192 + ks * 512);
                const half8 br = bread(wlds + 24576, 0, ks, lane);
                const half8 bz = bread(wlds + 24576, 1, ks, lane);
                const half8 bn = bread(wlds + 24576, 2, ks, lane);
                aR[0] = MFMA(a0, br, aR[0]); aR[1] = MFMA(a1, br, aR[1]);
                aZ[0] = MFMA(a0, bz, aZ[0]); aZ[1] = MFMA(a1, bz, aZ[1]);
                aNi[0] = MFMA(a0, bn, aNi[0]); aNi[1] = MFMA(a1, bn, aNi[1]);
            }
            #pragma unroll 4
            for (int ks = 0; ks < 16; ++ks) {
                const half8 a0 = *(const half8*)(A1 + ks * 512);
                const half8 a1 = *(const half8*)(A1 + 8192 + ks * 512);
                const half8 br = bread(wlds + 49152, 0, ks, lane);
                const half8 bz = bread(wlds + 49152, 1, ks, lane);
                const half8 bn = bread(wlds + 49152, 2, ks, lane);
                aR[0] = MFMA(a0, br, aR[0]); aR[1] = MFMA(a1, br, aR[1]);
                aZ[0] = MFMA(a0, bz, aZ[0]); aZ[1] = MFMA(a1, bz, aZ[1]);
                aNh[0] = MFMA(a0, bn, aNh[0]); aNh[1] = MFMA(a1, bn, aNh[1]);
            }
            half_t* ho = p.h1f[(s + 1) & 1];
            #pragma unroll
            for (int ms = 0; ms < 2; ++ms)
            #pragma unroll
            for (int r = 0; r < 4; ++r) {
                const int row16 = kg * 4 + r;
                const float rr = sig_(aR[ms][r] + bir), zz = sig_(aZ[ms][r] + biz);
                const float nn = tanhf(aNi[ms][r] + bin + rr * (aNh[ms][r] + bhn));
                const float h = (1.f - zz) * nn + zz * hp[ms][r];
                hp[ms][r] = h;
                ho[fragidx(g, wm * 2 + ms, jt, row16, jl)] = (half_t)h;
            }
        }
        xcd_barrier(slots, jt, ++bcnt);
    }

    // ============ transition: dec-init linear + reload dec weights ============
    float hpd[4];
    {
        floatx4 acc = {};
        const half_t* A = afrag(p.h1f[1], g, wv, lane);
        const half_t* Bb = p.Bdec + ((size_t)jt * 16) * 64 * 8 + lane * 8;
        #pragma unroll 4
        for (int ks = 0; ks < 16; ++ks) {
            const half8 a = *(const half8*)(A + ks * 512);
            const half8 b = *(const half8*)(Bb + ks * 512);
            acc = MFMA(a, b, acc);
        }
        const float bj = p.dec0b[j];
        half_t* ho = p.hdf[0];
        #pragma unroll
        for (int r = 0; r < 4; ++r) {
            const float h = acc[r] + bj;
            hpd[r] = h;
            ho[fragidx(g, wv, jt, kg * 4 + r, jl)] = (half_t)h;
        }
    }
    stage48(wlds, p.Bcwhh + (size_t)jt * 24576, tid);   // overwrite Whh0 slot

    float wR[9], wZ[9], wN[9];
    #pragma unroll
    for (int i = 0; i < 9; ++i) {
        wR[i] = p.cWih[(size_t)j * 9 + i];
        wZ[i] = p.cWih[(size_t)(512 + j) * 9 + i];
        wN[i] = p.cWih[(size_t)(1024 + j) * 9 + i];
    }
    const float dbr = p.cbih[j] + p.cbhh[j];
    const float dbz = p.cbih[512 + j] + p.cbhh[512 + j];
    const float dbn = p.cbih[1024 + j];
    const float dbhn = p.cbhh[1024 + j];
    const float fw = p.fcW[j], f0 = p.fcb[0];
    xcd_barrier(slots, jt, ++bcnt);

    // ===================== decoder =====================
    for (int s = 0; s < HOR; ++s) {
        if (tid < 64) {
            const float* lp = p.lvpart + ((size_t)(g * 2 + (s & 1)) * 32) * 64 + tid;
            float a = 0.f;
            #pragma unroll
            for (int ro = 0; ro < 32; ++ro) a += lp[ro * 64];
            lvsh[tid] = a;
        }
        __syncthreads();

        floatx4 aR = {}, aZ = {}, aN = {};
        const half_t* A = afrag(p.hdf[s & 1], g, wv, lane);
        #pragma unroll 4
        for (int ks = 0; ks < 16; ++ks) {
            const half8 a = *(const half8*)(A + ks * 512);
            const half8 br = bread(wlds, 0, ks, lane);
            const half8 bz = bread(wlds, 1, ks, lane);
            const half8 bn = bread(wlds, 2, ks, lane);
            aR = MFMA(a, br, aR);
            aZ = MFMA(a, bz, aZ);
            aN = MFMA(a, bn, aN);
        }
        half_t* ho = p.hdf[(s + 1) & 1];
        float v[4];
        #pragma unroll
        for (int r = 0; r < 4; ++r) {
            const int rloc = wv * 16 + kg * 4 + r;
            const int brw = g * 64 + rloc;
            const float x0 = lvsh[rloc] + f0;
            const float* sp = p.tff + ((size_t)brw * HOR + s) * 8;
            float xr = aR[r] + dbr + x0 * wR[0];
            float xz = aZ[r] + dbz + x0 * wZ[0];
            float xn = dbn + x0 * wN[0];
            #pragma unroll
            for (int i = 0; i < 8; ++i) {
                const float xi = sp[i];
                xr = fmaf(xi, wR[1 + i], xr);
                xz = fmaf(xi, wZ[1 + i], xz);
                xn = fmaf(xi, wN[1 + i], xn);
            }
            const float rr = sig_(xr), zz = sig_(xz);
            const float nn = tanhf(xn + rr * (aN[r] + dbhn));
            const float h = (1.f - zz) * nn + zz * hpd[r];
            hpd[r] = h;
            ho[fragidx(g, wv, jt, kg * 4 + r, jl)] = (half_t)h;
            v[r] = h * fw;
        }
        #pragma unroll
        for (int r = 0; r < 4; ++r) {
            v[r] += __shfl_xor(v[r], 1);
            v[r] += __shfl_xor(v[r], 2);
            v[r] += __shfl_xor(v[r], 4);
            v[r] += __shfl_xor(v[r], 8);
        }
        if (jl == 0) {
            #pragma unroll
            for (int r = 0; r < 4; ++r) {
                const int rloc = wv * 16 + kg * 4 + r;
                p.lvpart[((size_t)(g * 2 + ((s + 1) & 1)) * 32 + jt) * 64 + rloc] = v[r];
                atomicAdd(p.out + (size_t)(g * 64 + rloc) * HOR + s,
                          v[r] + (jt == 0 ? f0 : 0.f));
            }
        }
        xcd_barrier(slots, jt, ++bcnt);
    }
}

// ---------------------------------------------------------------------------
extern "C" void kernel_launch(void* const* d_in, const int* in_sizes, int n_in,
                              void* d_out, int out_size, void* d_ws, size_t ws_size,
                              hipStream_t stream)
{
    const float* src   = (const float*)d_in[0];
    const float* tff   = (const float*)d_in[1];
    const float* Wih0  = (const float*)d_in[2];
    const float* Whh0  = (const float*)d_in[3];
    const float* bih0  = (const float*)d_in[4];
    const float* bhh0  = (const float*)d_in[5];
    const float* Wih1  = (const float*)d_in[6];
    const float* Whh1  = (const float*)d_in[7];
    const float* bih1  = (const float*)d_in[8];
    const float* bhh1  = (const float*)d_in[9];
    const float* dec0W = (const float*)d_in[10];
    const float* dec0b = (const float*)d_in[11];
    const float* cWih  = (const float*)d_in[12];
    const float* cWhh  = (const float*)d_in[13];
    const float* cbih  = (const float*)d_in[14];
    const float* cbhh  = (const float*)d_in[15];
    const float* fcW   = (const float*)d_in[16];
    const float* fcb   = (const float*)d_in[17];
    float* out = (float*)d_out;
    float* ws  = (float*)d_ws;

    constexpr size_t NFRAG = 131072;   // one h frag buffer, float units (512KB)

    PP pp;
    size_t off = 0;
    // ---- zero region (single memset) ----
    pp.h0f[0] = (half_t*)(ws + off); off += NFRAG;
    pp.h1f[1] = (half_t*)(ws + off); off += NFRAG;
    pp.lvpart = ws + off; off += 8 * 2 * 32 * 64;          // [g][par][role][row]
    pp.bars   = (uint*)(ws + off); off += 8 * GBLK * 16;
    pp.tickets = (int*)(ws + off); off += 64;
    const size_t zero_floats = off;
    // ---- rest ----
    pp.h0f[1] = (half_t*)(ws + off); off += NFRAG;
    pp.h1f[0] = (half_t*)(ws + off); off += NFRAG;
    pp.hdf[0] = (half_t*)(ws + off); off += NFRAG;
    pp.hdf[1] = (half_t*)(ws + off); off += NFRAG;
    half_t* BL0   = (half_t*)(ws + off); off += 393216;   // 1536x512 fp16
    half_t* BWih1 = (half_t*)(ws + off); off += 393216;
    half_t* BWhh1 = (half_t*)(ws + off); off += 393216;
    half_t* Bcwhh = (half_t*)(ws + off); off += 393216;
    half_t* Bdec  = (half_t*)(ws + off); off += 131072;   // 512x512 fp16

    pp.BL0 = BL0; pp.BWih1 = BWih1; pp.BWhh1 = BWhh1; pp.Bcwhh = Bcwhh; pp.Bdec = Bdec;
    pp.src = src; pp.tff = tff; pp.Wih0 = Wih0;
    pp.bih0 = bih0; pp.bhh0 = bhh0; pp.bih1 = bih1; pp.bhh1 = bhh1;
    pp.dec0b = dec0b; pp.cWih = cWih; pp.cbih = cbih; pp.cbhh = cbhh;
    pp.fcW = fcW; pp.fcb = fcb; pp.out = out;

    // ---- prep ----
    hipMemsetAsync(ws, 0, zero_floats * sizeof(float), stream);
    hipMemsetAsync(out, 0, (size_t)BB * HOR * sizeof(float), stream);
    prep_w3<<<384, 256, 0, stream>>>(Whh0, BL0, 3);
    prep_w3<<<384, 256, 0, stream>>>(Wih1, BWih1, 3);
    prep_w3<<<384, 256, 0, stream>>>(Whh1, BWhh1, 3);
    prep_w3<<<384, 256, 0, stream>>>(cWhh, Bcwhh, 3);
    prep_w3<<<128, 256, 0, stream>>>(dec0W, Bdec, 1);
    lv_init_kernel<<<1, 512, 0, stream>>>(src, fcb, pp.lvpart);

    // ---- persistent cooperative kernel ----
    void* kargs[] = { (void*)&pp };
    hipLaunchCooperativeKernel((const void*)rnn_persist, dim3(NBLOCK), dim3(NTHREAD),
                               kargs, 0, stream);
}